// Round 13
// baseline (38.281 us; speedup 1.0000x reference)
//
#include <hip/hip_runtime.h>
#include <hip/hip_bf16.h>

#define BT 16      // B*T
#define NN 256     // nodes
#define DD 128     // feature dim
#define MROWS (BT*NN)   // 4096 total rows

typedef __bf16 bf16x8 __attribute__((ext_vector_type(8)));
typedef float  f32x4  __attribute__((ext_vector_type(4)));

#define LREL(z) ((z) >= 0.0f ? (z) : 0.2f * (z))
#define WTS 136   // LDS row stride (bf16): 272B -> frag reads 2 lanes/bank (free)

// ============ Kernel 1: two-stage GEMM, weights transposed in LDS =========
// 512 blocks x 256 thr. Block = (16-row chunk, parity).
//   phase A : coop-load W coalesced -> wt[n][k] (bf16, transposed)
//   stage 1 : h = x@W + bias -> LDS hs + (parity 0) hbuf; B-frags via ds_read_b128
//   phase B : coop-load W1[parity] -> wt (overwrite)
//   stage 2 : parity 0 -> a = h@W1a ; parity 1 -> b = h@W1b + att_b1
// Eliminates ALL per-lane strided global weight loads (128 -> 0 per lane).
__global__ __launch_bounds__(256) void gemm2_kernel(
        const float* __restrict__ x, const float* __restrict__ weight,
        const float* __restrict__ bias, const float* __restrict__ attw1,
        const float* __restrict__ attb1,
        __bf16* __restrict__ hbuf, __bf16* __restrict__ abuf,
        __bf16* __restrict__ bbuf) {
    int tid = threadIdx.x;
    int w = tid >> 6, l = tid & 63;
    int chunk = blockIdx.x >> 1, parity = blockIdx.x & 1;
    int row0 = chunk * 16;
    int lrow = l & 15, lk8 = (l >> 4) * 8;

    __shared__ __align__(16) __bf16 hs[16][WTS];
    __shared__ __align__(16) __bf16 wt[128 * WTS];   // W^T then W1x^T

    // ---- phase A: W -> wt (coalesced read, transposed bf16 write) ----
    {
        const float4* W4 = (const float4*)weight;
#pragma unroll
        for (int u = 0; u < 16; ++u) {
            int f = u * 256 + tid;            // float4 index, lane-consecutive
            float4 v = W4[f];
            int n0 = (f * 4) & 127, k = (f * 4) >> 7;
            wt[(n0 + 0) * WTS + k] = (__bf16)v.x;
            wt[(n0 + 1) * WTS + k] = (__bf16)v.y;
            wt[(n0 + 2) * WTS + k] = (__bf16)v.z;
            wt[(n0 + 3) * WTS + k] = (__bf16)v.w;
        }
    }

    // ---- A fragments from x (contiguous, unchanged) ----
    const float* abase = x + (size_t)(row0 + lrow) * DD + lk8;
    bf16x8 af[4];
#pragma unroll
    for (int kt = 0; kt < 4; ++kt) {
        float4 u0 = *(const float4*)(abase + 32 * kt);
        float4 u1 = *(const float4*)(abase + 32 * kt + 4);
        af[kt][0]=(__bf16)u0.x; af[kt][1]=(__bf16)u0.y;
        af[kt][2]=(__bf16)u0.z; af[kt][3]=(__bf16)u0.w;
        af[kt][4]=(__bf16)u1.x; af[kt][5]=(__bf16)u1.y;
        af[kt][6]=(__bf16)u1.z; af[kt][7]=(__bf16)u1.w;
    }
    __syncthreads();

    // ---- stage 1: h tiles; wave w does n-tiles w and w+4 ----
#pragma unroll
    for (int s = 0; s < 2; ++s) {
        int ncol = (w + 4 * s) * 16 + lrow;
        bf16x8 wf[4];
#pragma unroll
        for (int kt = 0; kt < 4; ++kt)
            wf[kt] = *(const bf16x8*)&wt[ncol * WTS + lk8 + 32 * kt];
        f32x4 acc = {0.f, 0.f, 0.f, 0.f};
        acc = __builtin_amdgcn_mfma_f32_16x16x32_bf16(af[0], wf[0], acc, 0, 0, 0);
        acc = __builtin_amdgcn_mfma_f32_16x16x32_bf16(af[1], wf[1], acc, 0, 0, 0);
        acc = __builtin_amdgcn_mfma_f32_16x16x32_bf16(af[2], wf[2], acc, 0, 0, 0);
        acc = __builtin_amdgcn_mfma_f32_16x16x32_bf16(af[3], wf[3], acc, 0, 0, 0);

        float bb = bias[ncol];
        int rloc = (l >> 4) * 4;               // D: row=(l>>4)*4+r, col=lane&15
        __bf16* hout = hbuf + (size_t)(row0 + rloc) * DD + ncol;
#pragma unroll
        for (int r = 0; r < 4; ++r) {
            __bf16 hv = (__bf16)(acc[r] + bb);
            hs[rloc + r][ncol] = hv;
            if (parity == 0) hout[(size_t)r * DD] = hv;
        }
    }
    __syncthreads();   // stage-1 reads of wt done; hs complete

    // ---- phase B: W1[parity] -> wt ----
    {
        const float4* W14 = (const float4*)(attw1 + (size_t)parity * DD * DD);
#pragma unroll
        for (int u = 0; u < 16; ++u) {
            int f = u * 256 + tid;
            float4 v = W14[f];
            int n0 = (f * 4) & 127, k = (f * 4) >> 7;
            wt[(n0 + 0) * WTS + k] = (__bf16)v.x;
            wt[(n0 + 1) * WTS + k] = (__bf16)v.y;
            wt[(n0 + 2) * WTS + k] = (__bf16)v.z;
            wt[(n0 + 3) * WTS + k] = (__bf16)v.w;
        }
    }

    bf16x8 ha[4];
#pragma unroll
    for (int kt = 0; kt < 4; ++kt)
        ha[kt] = *(const bf16x8*)(&hs[lrow][lk8 + 32 * kt]);
    __syncthreads();

    // ---- stage 2: a (parity 0) or b (parity 1) ----
#pragma unroll
    for (int s = 0; s < 2; ++s) {
        int ncol = (w + 4 * s) * 16 + lrow;
        bf16x8 w1f[4];
#pragma unroll
        for (int kt = 0; kt < 4; ++kt)
            w1f[kt] = *(const bf16x8*)&wt[ncol * WTS + lk8 + 32 * kt];
        f32x4 acc = {0.f, 0.f, 0.f, 0.f};
        acc = __builtin_amdgcn_mfma_f32_16x16x32_bf16(ha[0], w1f[0], acc, 0, 0, 0);
        acc = __builtin_amdgcn_mfma_f32_16x16x32_bf16(ha[1], w1f[1], acc, 0, 0, 0);
        acc = __builtin_amdgcn_mfma_f32_16x16x32_bf16(ha[2], w1f[2], acc, 0, 0, 0);
        acc = __builtin_amdgcn_mfma_f32_16x16x32_bf16(ha[3], w1f[3], acc, 0, 0, 0);

        float bb = parity ? attb1[ncol] : 0.f;
        __bf16* dst = (parity ? bbuf : abuf) + (size_t)(row0 + (l >> 4) * 4) * DD + ncol;
#pragma unroll
        for (int r = 0; r < 4; ++r)
            dst[(size_t)r * DD] = (__bf16)(acc[r] + bb);
    }
}

// ============ Kernel 2: sparse attn + LN + ReLU (R11 verbatim) ============
__global__ __launch_bounds__(256) void attn_kernel(
        const __bf16* __restrict__ hbuf, const __bf16* __restrict__ abuf,
        const __bf16* __restrict__ bbuf, const float* __restrict__ x,
        const float* __restrict__ adj, const float* __restrict__ w2,
        const float* __restrict__ gamma, const float* __restrict__ beta,
        float* __restrict__ out) {
    int tid = threadIdx.x;
    int w = tid >> 6, l = tid & 63;
    int i  = (blockIdx.x & 63) * 4 + w;
    int bt = blockIdx.x >> 6;

    __shared__ int nbr_l[4][64];

    int cnt = 0;
    const float* adjrow = adj + (size_t)i * NN;
    for (int jt = 0; jt < NN / 64; ++jt) {
        int j = jt * 64 + l;
        float v = adjrow[j];
        unsigned long long mask = __ballot(v != 0.f);
        if (v != 0.f) {
            int pos = cnt + __popcll(mask & ((1ull << l) - 1ull));
            if (pos < 64) nbr_l[w][pos] = j;
        }
        cnt += __popcll(mask);
    }
    cnt = min(cnt, 64);
    int jreg = nbr_l[w][l];

    const __bf16* arow = abuf + (size_t)(bt * NN + i) * DD;
    float a0 = (float)arow[l], a1 = (float)arow[l + 64];
    float w20 = w2[l],  w21 = w2[l + 64];
    const __bf16* bbase = bbuf + (size_t)bt * NN * DD;

    float m = -3.0e38f, myp = 0.f;
    int c = 0;
    for (; c + 3 < cnt; c += 4) {
        int j0 = __shfl(jreg, c),     j1 = __shfl(jreg, c + 1);
        int j2 = __shfl(jreg, c + 2), j3 = __shfl(jreg, c + 3);
        const __bf16* B0 = bbase + (size_t)j0 * DD;
        const __bf16* B1 = bbase + (size_t)j1 * DD;
        const __bf16* B2 = bbase + (size_t)j2 * DD;
        const __bf16* B3 = bbase + (size_t)j3 * DD;
        float p0 = LREL(a0 + (float)B0[l]) * w20 + LREL(a1 + (float)B0[l + 64]) * w21;
        float p1 = LREL(a0 + (float)B1[l]) * w20 + LREL(a1 + (float)B1[l + 64]) * w21;
        float p2 = LREL(a0 + (float)B2[l]) * w20 + LREL(a1 + (float)B2[l + 64]) * w21;
        float p3 = LREL(a0 + (float)B3[l]) * w20 + LREL(a1 + (float)B3[l + 64]) * w21;
#pragma unroll
        for (int off = 32; off; off >>= 1) {
            p0 += __shfl_xor(p0, off);
            p1 += __shfl_xor(p1, off);
            p2 += __shfl_xor(p2, off);
            p3 += __shfl_xor(p3, off);
        }
        myp = (l == c)     ? p0 : myp;
        myp = (l == c + 1) ? p1 : myp;
        myp = (l == c + 2) ? p2 : myp;
        myp = (l == c + 3) ? p3 : myp;
        m = fmaxf(m, fmaxf(fmaxf(p0, p1), fmaxf(p2, p3)));
    }
    for (; c < cnt; ++c) {
        int j0 = __shfl(jreg, c);
        const __bf16* B0 = bbase + (size_t)j0 * DD;
        float p0 = LREL(a0 + (float)B0[l]) * w20 + LREL(a1 + (float)B0[l + 64]) * w21;
#pragma unroll
        for (int off = 32; off; off >>= 1) p0 += __shfl_xor(p0, off);
        myp = (l == c) ? p0 : myp;
        m = fmaxf(m, p0);
    }

    float wgt = (l < cnt) ? __expf(myp - m) : 0.f;
    float dsum = wgt;
#pragma unroll
    for (int off = 32; off; off >>= 1) dsum += __shfl_xor(dsum, off);
    float inv = 1.f / dsum;

    const __bf16* hbase = hbuf + (size_t)bt * NN * DD;
    float acc0 = 0.f, acc1 = 0.f;
    c = 0;
    for (; c + 3 < cnt; c += 4) {
        float wc0 = __shfl(wgt, c),     wc1 = __shfl(wgt, c + 1);
        float wc2 = __shfl(wgt, c + 2), wc3 = __shfl(wgt, c + 3);
        int j0 = __shfl(jreg, c),     j1 = __shfl(jreg, c + 1);
        int j2 = __shfl(jreg, c + 2), j3 = __shfl(jreg, c + 3);
        const __bf16* H0 = hbase + (size_t)j0 * DD;
        const __bf16* H1 = hbase + (size_t)j1 * DD;
        const __bf16* H2 = hbase + (size_t)j2 * DD;
        const __bf16* H3 = hbase + (size_t)j3 * DD;
        acc0 += wc0 * (float)H0[l]      + wc1 * (float)H1[l]
              + wc2 * (float)H2[l]      + wc3 * (float)H3[l];
        acc1 += wc0 * (float)H0[l + 64] + wc1 * (float)H1[l + 64]
              + wc2 * (float)H2[l + 64] + wc3 * (float)H3[l + 64];
    }
    for (; c < cnt; ++c) {
        float wc = __shfl(wgt, c);
        int j = __shfl(jreg, c);
        const __bf16* H = hbase + (size_t)j * DD;
        acc0 += wc * (float)H[l];
        acc1 += wc * (float)H[l + 64];
    }

    const float* xrow = x + (size_t)(bt * NN + i) * DD;
    float y0 = acc0 * inv + xrow[l];
    float y1 = acc1 * inv + xrow[l + 64];

    float s = y0 + y1;
#pragma unroll
    for (int off = 32; off; off >>= 1) s += __shfl_xor(s, off);
    float mu = s * (1.0f / 128.0f);
    float v0 = y0 - mu, v1 = y1 - mu;
    float vs = v0 * v0 + v1 * v1;
#pragma unroll
    for (int off = 32; off; off >>= 1) vs += __shfl_xor(vs, off);
    float rstd = rsqrtf(vs * (1.0f / 128.0f) + 1e-5f);

    float o0 = v0 * rstd * gamma[l]      + beta[l];
    float o1 = v1 * rstd * gamma[l + 64] + beta[l + 64];

    float* orow = out + (size_t)(bt * NN + i) * DD;
    orow[l]      = fmaxf(o0, 0.0f);
    orow[l + 64] = fmaxf(o1, 0.0f);
}

extern "C" void kernel_launch(void* const* d_in, const int* in_sizes, int n_in,
                              void* d_out, int out_size, void* d_ws, size_t ws_size,
                              hipStream_t stream) {
    const float* x      = (const float*)d_in[0];
    const float* adj    = (const float*)d_in[1];
    const float* weight = (const float*)d_in[2];
    const float* bias   = (const float*)d_in[3];
    const float* attw1  = (const float*)d_in[4];
    const float* attb1  = (const float*)d_in[5];
    const float* attw2  = (const float*)d_in[6];
    // d_in[7] = att_b2: uniform score shift -> cancels in softmax
    const float* gamma  = (const float*)d_in[8];
    const float* beta   = (const float*)d_in[9];
    float* out = (float*)d_out;

    char* p = (char*)d_ws;
    __bf16* hbuf = (__bf16*)p;        p += (size_t)MROWS * DD * 2;
    __bf16* abuf = (__bf16*)p;        p += (size_t)MROWS * DD * 2;
    __bf16* bbuf = (__bf16*)p;

    gemm2_kernel<<<MROWS / 16 * 2, 256, 0, stream>>>(x, weight, bias, attw1, attb1,
                                                     hbuf, abuf, bbuf);
    attn_kernel<<<NN / 4 * BT, 256, 0, stream>>>(hbuf, abuf, bbuf, x, adj,
                                                 attw2, gamma, beta, out);
}

// Round 14
// 26.953 us; speedup vs baseline: 1.4203x; 1.4203x over previous
//
#include <hip/hip_runtime.h>
#include <hip/hip_bf16.h>

#define BT 16      // B*T
#define NN 256     // nodes
#define DD 128     // feature dim
#define MROWS (BT*NN)   // 4096 total rows

typedef __bf16 bf16x8 __attribute__((ext_vector_type(8)));
typedef __bf16 bf16x2 __attribute__((ext_vector_type(2)));
typedef float  f32x4  __attribute__((ext_vector_type(4)));

#define LREL(z) ((z) >= 0.0f ? (z) : 0.2f * (z))
#define HS_STRIDE 136   // bf16 elems per row: 272B, 16B-aligned rows

// ============ Kernel 1: two-stage GEMM (R11 verbatim) =====================
// 512 blocks x 256 thr (2 waves/SIMD). Block = (16-row chunk, parity).
//   stage 1 (all blocks): h = x@W + bias -> LDS (bf16); parity 0 also -> hbuf
//   stage 2: parity 0 -> a = h@W1a ; parity 1 -> b = h@W1b + att_b1
__global__ __launch_bounds__(256) void gemm2_kernel(
        const float* __restrict__ x, const float* __restrict__ weight,
        const float* __restrict__ bias, const float* __restrict__ attw1,
        const float* __restrict__ attb1,
        __bf16* __restrict__ hbuf, __bf16* __restrict__ abuf,
        __bf16* __restrict__ bbuf) {
    int tid = threadIdx.x;
    int w = tid >> 6, l = tid & 63;
    int chunk = blockIdx.x >> 1, parity = blockIdx.x & 1;
    int row0 = chunk * 16;
    int lrow = l & 15, lk8 = (l >> 4) * 8;

    __shared__ __align__(16) __bf16 hs[16][HS_STRIDE];

    // ---- A fragments from x: lane row (l&15), k = lk8 + 32*kt + j ----
    const float* abase = x + (size_t)(row0 + lrow) * DD + lk8;
    bf16x8 af[4];
#pragma unroll
    for (int kt = 0; kt < 4; ++kt) {
        float4 u0 = *(const float4*)(abase + 32 * kt);
        float4 u1 = *(const float4*)(abase + 32 * kt + 4);
        af[kt][0]=(__bf16)u0.x; af[kt][1]=(__bf16)u0.y;
        af[kt][2]=(__bf16)u0.z; af[kt][3]=(__bf16)u0.w;
        af[kt][4]=(__bf16)u1.x; af[kt][5]=(__bf16)u1.y;
        af[kt][6]=(__bf16)u1.z; af[kt][7]=(__bf16)u1.w;
    }

    // ---- stage 1: h tiles; wave w does n-tiles w and w+4 ----
#pragma unroll
    for (int s = 0; s < 2; ++s) {
        int n0 = (w + 4 * s) * 16;
        int ncol = n0 + lrow;
        bf16x8 wf[4];
#pragma unroll
        for (int kt = 0; kt < 4; ++kt) {
            const float* wp = weight + (size_t)(lk8 + 32 * kt) * DD + ncol;
#pragma unroll
            for (int j = 0; j < 8; ++j)
                wf[kt][j] = (__bf16)wp[(size_t)j * DD];
        }
        f32x4 acc = {0.f, 0.f, 0.f, 0.f};
        acc = __builtin_amdgcn_mfma_f32_16x16x32_bf16(af[0], wf[0], acc, 0, 0, 0);
        acc = __builtin_amdgcn_mfma_f32_16x16x32_bf16(af[1], wf[1], acc, 0, 0, 0);
        acc = __builtin_amdgcn_mfma_f32_16x16x32_bf16(af[2], wf[2], acc, 0, 0, 0);
        acc = __builtin_amdgcn_mfma_f32_16x16x32_bf16(af[3], wf[3], acc, 0, 0, 0);

        float bb = bias[ncol];
        int rloc = (l >> 4) * 4;               // D: row=(l>>4)*4+r, col=lane&15
        __bf16* hout = hbuf + (size_t)(row0 + rloc) * DD + ncol;
#pragma unroll
        for (int r = 0; r < 4; ++r) {
            __bf16 hv = (__bf16)(acc[r] + bb);
            hs[rloc + r][ncol] = hv;
            if (parity == 0) hout[(size_t)r * DD] = hv;
        }
    }
    __syncthreads();

    // ---- stage 2 (h2 = parity): a or b tiles from LDS h ----
    bf16x8 ha[4];
#pragma unroll
    for (int kt = 0; kt < 4; ++kt)
        ha[kt] = *(const bf16x8*)(&hs[lrow][lk8 + 32 * kt]);

#pragma unroll
    for (int s = 0; s < 2; ++s) {
        int n0 = (w + 4 * s) * 16;
        int ncol = n0 + lrow;
        bf16x8 w1f[4];
#pragma unroll
        for (int kt = 0; kt < 4; ++kt) {
            const float* wp = attw1 + (size_t)(parity * DD + lk8 + 32 * kt) * DD + ncol;
#pragma unroll
            for (int j = 0; j < 8; ++j)
                w1f[kt][j] = (__bf16)wp[(size_t)j * DD];
        }
        f32x4 acc = {0.f, 0.f, 0.f, 0.f};
        acc = __builtin_amdgcn_mfma_f32_16x16x32_bf16(ha[0], w1f[0], acc, 0, 0, 0);
        acc = __builtin_amdgcn_mfma_f32_16x16x32_bf16(ha[1], w1f[1], acc, 0, 0, 0);
        acc = __builtin_amdgcn_mfma_f32_16x16x32_bf16(ha[2], w1f[2], acc, 0, 0, 0);
        acc = __builtin_amdgcn_mfma_f32_16x16x32_bf16(ha[3], w1f[3], acc, 0, 0, 0);

        float bb = parity ? attb1[ncol] : 0.f;
        __bf16* dst = (parity ? bbuf : abuf) + (size_t)(row0 + (l >> 4) * 4) * DD + ncol;
#pragma unroll
        for (int r = 0; r < 4; ++r)
            dst[(size_t)r * DD] = (__bf16)(acc[r] + bb);
    }
}

// ============ Kernel 2: sparse attn + LN + ReLU ===========================
// R11 skeleton; lane l now owns dims {2l, 2l+1} -> every per-row access is
// ONE 4B bf16x2 (or 8B float2) load instead of two scalar loads.
__global__ __launch_bounds__(256) void attn_kernel(
        const __bf16* __restrict__ hbuf, const __bf16* __restrict__ abuf,
        const __bf16* __restrict__ bbuf, const float* __restrict__ x,
        const float* __restrict__ adj, const float* __restrict__ w2,
        const float* __restrict__ gamma, const float* __restrict__ beta,
        float* __restrict__ out) {
    int tid = threadIdx.x;
    int w = tid >> 6, l = tid & 63;
    int i  = (blockIdx.x & 63) * 4 + w;
    int bt = blockIdx.x >> 6;
    int d2 = 2 * l;                 // this lane's dim pair {d2, d2+1}

    __shared__ int nbr_l[4][64];

    // ---- in-wave adjacency compaction (adj rows L2-hot) ----
    int cnt = 0;
    const float* adjrow = adj + (size_t)i * NN;
    for (int jt = 0; jt < NN / 64; ++jt) {
        int j = jt * 64 + l;
        float v = adjrow[j];
        unsigned long long mask = __ballot(v != 0.f);
        if (v != 0.f) {
            int pos = cnt + __popcll(mask & ((1ull << l) - 1ull));
            if (pos < 64) nbr_l[w][pos] = j;
        }
        cnt += __popcll(mask);
    }
    cnt = min(cnt, 64);
    int jreg = nbr_l[w][l];         // lane l holds neighbor l's index

    bf16x2 av = *(const bf16x2*)(abuf + (size_t)(bt * NN + i) * DD + d2);
    float a0 = (float)av[0], a1 = (float)av[1];
    float2 wv = *(const float2*)(w2 + d2);
    float w20 = wv.x, w21 = wv.y;
    const __bf16* bbase = bbuf + (size_t)bt * NN * DD;

    // ---- scores: 4 neighbors/iter, 4 independent reduce chains ----
    float m = -3.0e38f, myp = 0.f;
    int c = 0;
    for (; c + 3 < cnt; c += 4) {
        int j0 = __shfl(jreg, c),     j1 = __shfl(jreg, c + 1);
        int j2 = __shfl(jreg, c + 2), j3 = __shfl(jreg, c + 3);
        bf16x2 b0 = *(const bf16x2*)(bbase + (size_t)j0 * DD + d2);
        bf16x2 b1 = *(const bf16x2*)(bbase + (size_t)j1 * DD + d2);
        bf16x2 b2 = *(const bf16x2*)(bbase + (size_t)j2 * DD + d2);
        bf16x2 b3 = *(const bf16x2*)(bbase + (size_t)j3 * DD + d2);
        float p0 = LREL(a0 + (float)b0[0]) * w20 + LREL(a1 + (float)b0[1]) * w21;
        float p1 = LREL(a0 + (float)b1[0]) * w20 + LREL(a1 + (float)b1[1]) * w21;
        float p2 = LREL(a0 + (float)b2[0]) * w20 + LREL(a1 + (float)b2[1]) * w21;
        float p3 = LREL(a0 + (float)b3[0]) * w20 + LREL(a1 + (float)b3[1]) * w21;
#pragma unroll
        for (int off = 32; off; off >>= 1) {
            p0 += __shfl_xor(p0, off);
            p1 += __shfl_xor(p1, off);
            p2 += __shfl_xor(p2, off);
            p3 += __shfl_xor(p3, off);
        }
        myp = (l == c)     ? p0 : myp;
        myp = (l == c + 1) ? p1 : myp;
        myp = (l == c + 2) ? p2 : myp;
        myp = (l == c + 3) ? p3 : myp;
        m = fmaxf(m, fmaxf(fmaxf(p0, p1), fmaxf(p2, p3)));
    }
    for (; c < cnt; ++c) {
        int j0 = __shfl(jreg, c);
        bf16x2 b0 = *(const bf16x2*)(bbase + (size_t)j0 * DD + d2);
        float p0 = LREL(a0 + (float)b0[0]) * w20 + LREL(a1 + (float)b0[1]) * w21;
#pragma unroll
        for (int off = 32; off; off >>= 1) p0 += __shfl_xor(p0, off);
        myp = (l == c) ? p0 : myp;
        m = fmaxf(m, p0);
    }

    float wgt = (l < cnt) ? __expf(myp - m) : 0.f;
    float dsum = wgt;
#pragma unroll
    for (int off = 32; off; off >>= 1) dsum += __shfl_xor(dsum, off);
    float inv = 1.f / dsum;

    // ---- aggregate: 4 neighbors/iter ----
    const __bf16* hbase = hbuf + (size_t)bt * NN * DD;
    float acc0 = 0.f, acc1 = 0.f;
    c = 0;
    for (; c + 3 < cnt; c += 4) {
        float wc0 = __shfl(wgt, c),     wc1 = __shfl(wgt, c + 1);
        float wc2 = __shfl(wgt, c + 2), wc3 = __shfl(wgt, c + 3);
        int j0 = __shfl(jreg, c),     j1 = __shfl(jreg, c + 1);
        int j2 = __shfl(jreg, c + 2), j3 = __shfl(jreg, c + 3);
        bf16x2 h0 = *(const bf16x2*)(hbase + (size_t)j0 * DD + d2);
        bf16x2 h1 = *(const bf16x2*)(hbase + (size_t)j1 * DD + d2);
        bf16x2 h2 = *(const bf16x2*)(hbase + (size_t)j2 * DD + d2);
        bf16x2 h3 = *(const bf16x2*)(hbase + (size_t)j3 * DD + d2);
        acc0 += wc0 * (float)h0[0] + wc1 * (float)h1[0]
              + wc2 * (float)h2[0] + wc3 * (float)h3[0];
        acc1 += wc0 * (float)h0[1] + wc1 * (float)h1[1]
              + wc2 * (float)h2[1] + wc3 * (float)h3[1];
    }
    for (; c < cnt; ++c) {
        float wc = __shfl(wgt, c);
        int j = __shfl(jreg, c);
        bf16x2 h0 = *(const bf16x2*)(hbase + (size_t)j * DD + d2);
        acc0 += wc * (float)h0[0];
        acc1 += wc * (float)h0[1];
    }

    // ---- residual + LayerNorm + ReLU ----
    float2 xv = *(const float2*)(x + (size_t)(bt * NN + i) * DD + d2);
    float y0 = acc0 * inv + xv.x;
    float y1 = acc1 * inv + xv.y;

    float s = y0 + y1;
#pragma unroll
    for (int off = 32; off; off >>= 1) s += __shfl_xor(s, off);
    float mu = s * (1.0f / 128.0f);
    float v0 = y0 - mu, v1 = y1 - mu;
    float vs = v0 * v0 + v1 * v1;
#pragma unroll
    for (int off = 32; off; off >>= 1) vs += __shfl_xor(vs, off);
    float rstd = rsqrtf(vs * (1.0f / 128.0f) + 1e-5f);

    float2 gv = *(const float2*)(gamma + d2);
    float2 bv = *(const float2*)(beta + d2);
    float2 ov;
    ov.x = fmaxf(v0 * rstd * gv.x + bv.x, 0.0f);
    ov.y = fmaxf(v1 * rstd * gv.y + bv.y, 0.0f);
    *(float2*)(out + (size_t)(bt * NN + i) * DD + d2) = ov;
}

extern "C" void kernel_launch(void* const* d_in, const int* in_sizes, int n_in,
                              void* d_out, int out_size, void* d_ws, size_t ws_size,
                              hipStream_t stream) {
    const float* x      = (const float*)d_in[0];
    const float* adj    = (const float*)d_in[1];
    const float* weight = (const float*)d_in[2];
    const float* bias   = (const float*)d_in[3];
    const float* attw1  = (const float*)d_in[4];
    const float* attb1  = (const float*)d_in[5];
    const float* attw2  = (const float*)d_in[6];
    // d_in[7] = att_b2: uniform score shift -> cancels in softmax
    const float* gamma  = (const float*)d_in[8];
    const float* beta   = (const float*)d_in[9];
    float* out = (float*)d_out;

    char* p = (char*)d_ws;
    __bf16* hbuf = (__bf16*)p;        p += (size_t)MROWS * DD * 2;
    __bf16* abuf = (__bf16*)p;        p += (size_t)MROWS * DD * 2;
    __bf16* bbuf = (__bf16*)p;

    gemm2_kernel<<<MROWS / 16 * 2, 256, 0, stream>>>(x, weight, bias, attw1, attb1,
                                                     hbuf, abuf, bbuf);
    attn_kernel<<<NN / 4 * BT, 256, 0, stream>>>(hbuf, abuf, bbuf, x, adj,
                                                 attw2, gamma, beta, out);
}

// Round 15
// 24.175 us; speedup vs baseline: 1.5835x; 1.1149x over previous
//
#include <hip/hip_runtime.h>
#include <hip/hip_bf16.h>

#define BT 16      // B*T
#define NN 256     // nodes
#define DD 128     // feature dim
#define MROWS (BT*NN)   // 4096 total rows

typedef __bf16 bf16x8 __attribute__((ext_vector_type(8)));
typedef __bf16 bf16x2 __attribute__((ext_vector_type(2)));
typedef float  f32x4  __attribute__((ext_vector_type(4)));

#define LREL(z) ((z) >= 0.0f ? (z) : 0.2f * (z))
#define HS_STRIDE 136   // bf16 elems per row: 272B, 16B-aligned rows

// ============ Kernel 1: two-stage GEMM + adjacency compaction =============
// 512 blocks x 256 thr. Block = (16-row chunk, parity); chunk in [0,256).
//   extra: wave 0 of parity-0 blocks compacts adjacency row `chunk` -> nbr
//   stage 1 (all blocks): h = x@W + bias -> LDS (bf16); parity 0 also -> hbuf
//   stage 2: parity 0 -> a = h@W1a ; parity 1 -> b = h@W1b + att_b1
__global__ __launch_bounds__(256) void gemm2_kernel(
        const float* __restrict__ x, const float* __restrict__ weight,
        const float* __restrict__ bias, const float* __restrict__ attw1,
        const float* __restrict__ attb1, const float* __restrict__ adj,
        __bf16* __restrict__ hbuf, __bf16* __restrict__ abuf,
        __bf16* __restrict__ bbuf, int* __restrict__ nbr,
        int* __restrict__ nbr_cnt) {
    int tid = threadIdx.x;
    int w = tid >> 6, l = tid & 63;
    int chunk = blockIdx.x >> 1, parity = blockIdx.x & 1;
    int row0 = chunk * 16;
    int lrow = l & 15, lk8 = (l >> 4) * 8;

    __shared__ __align__(16) __bf16 hs[16][HS_STRIDE];

    // ---- adjacency compaction for node `chunk` (wave 0, parity 0 only) ----
    if (parity == 0 && w == 0) {
        int i = chunk;                 // chunk spans [0,256) == all nodes
        int cnt = 0;
        const float* adjrow = adj + (size_t)i * NN;
        for (int jt = 0; jt < NN / 64; ++jt) {
            int j = jt * 64 + l;
            float v = adjrow[j];
            unsigned long long mask = __ballot(v != 0.f);
            if (v != 0.f) {
                int pos = cnt + __popcll(mask & ((1ull << l) - 1ull));
                if (pos < 64) nbr[i * 64 + pos] = j;
            }
            cnt += __popcll(mask);
        }
        if (l == 0) nbr_cnt[i] = min(cnt, 64);
    }

    // ---- A fragments from x: lane row (l&15), k = lk8 + 32*kt + j ----
    const float* abase = x + (size_t)(row0 + lrow) * DD + lk8;
    bf16x8 af[4];
#pragma unroll
    for (int kt = 0; kt < 4; ++kt) {
        float4 u0 = *(const float4*)(abase + 32 * kt);
        float4 u1 = *(const float4*)(abase + 32 * kt + 4);
        af[kt][0]=(__bf16)u0.x; af[kt][1]=(__bf16)u0.y;
        af[kt][2]=(__bf16)u0.z; af[kt][3]=(__bf16)u0.w;
        af[kt][4]=(__bf16)u1.x; af[kt][5]=(__bf16)u1.y;
        af[kt][6]=(__bf16)u1.z; af[kt][7]=(__bf16)u1.w;
    }

    // ---- stage 1: h tiles; wave w does n-tiles w and w+4 ----
#pragma unroll
    for (int s = 0; s < 2; ++s) {
        int n0 = (w + 4 * s) * 16;
        int ncol = n0 + lrow;
        bf16x8 wf[4];
#pragma unroll
        for (int kt = 0; kt < 4; ++kt) {
            const float* wp = weight + (size_t)(lk8 + 32 * kt) * DD + ncol;
#pragma unroll
            for (int j = 0; j < 8; ++j)
                wf[kt][j] = (__bf16)wp[(size_t)j * DD];
        }
        f32x4 acc = {0.f, 0.f, 0.f, 0.f};
        acc = __builtin_amdgcn_mfma_f32_16x16x32_bf16(af[0], wf[0], acc, 0, 0, 0);
        acc = __builtin_amdgcn_mfma_f32_16x16x32_bf16(af[1], wf[1], acc, 0, 0, 0);
        acc = __builtin_amdgcn_mfma_f32_16x16x32_bf16(af[2], wf[2], acc, 0, 0, 0);
        acc = __builtin_amdgcn_mfma_f32_16x16x32_bf16(af[3], wf[3], acc, 0, 0, 0);

        float bb = bias[ncol];
        int rloc = (l >> 4) * 4;               // D: row=(l>>4)*4+r, col=lane&15
        __bf16* hout = hbuf + (size_t)(row0 + rloc) * DD + ncol;
#pragma unroll
        for (int r = 0; r < 4; ++r) {
            __bf16 hv = (__bf16)(acc[r] + bb);
            hs[rloc + r][ncol] = hv;
            if (parity == 0) hout[(size_t)r * DD] = hv;
        }
    }
    __syncthreads();

    // ---- stage 2 (h2 = parity): a or b tiles from LDS h ----
    bf16x8 ha[4];
#pragma unroll
    for (int kt = 0; kt < 4; ++kt)
        ha[kt] = *(const bf16x8*)(&hs[lrow][lk8 + 32 * kt]);

#pragma unroll
    for (int s = 0; s < 2; ++s) {
        int n0 = (w + 4 * s) * 16;
        int ncol = n0 + lrow;
        bf16x8 w1f[4];
#pragma unroll
        for (int kt = 0; kt < 4; ++kt) {
            const float* wp = attw1 + (size_t)(parity * DD + lk8 + 32 * kt) * DD + ncol;
#pragma unroll
            for (int j = 0; j < 8; ++j)
                w1f[kt][j] = (__bf16)wp[(size_t)j * DD];
        }
        f32x4 acc = {0.f, 0.f, 0.f, 0.f};
        acc = __builtin_amdgcn_mfma_f32_16x16x32_bf16(ha[0], w1f[0], acc, 0, 0, 0);
        acc = __builtin_amdgcn_mfma_f32_16x16x32_bf16(ha[1], w1f[1], acc, 0, 0, 0);
        acc = __builtin_amdgcn_mfma_f32_16x16x32_bf16(ha[2], w1f[2], acc, 0, 0, 0);
        acc = __builtin_amdgcn_mfma_f32_16x16x32_bf16(ha[3], w1f[3], acc, 0, 0, 0);

        float bb = parity ? attb1[ncol] : 0.f;
        __bf16* dst = (parity ? bbuf : abuf) + (size_t)(row0 + (l >> 4) * 4) * DD + ncol;
#pragma unroll
        for (int r = 0; r < 4; ++r)
            dst[(size_t)r * DD] = (__bf16)(acc[r] + bb);
    }
}

// ============ Kernel 2: sparse attn, ONLINE softmax, + LN + ReLU ==========
// 4 waves/block, one (node, bt) per wave; lane l owns dims {2l, 2l+1}.
// Single neighbor loop: b-row and h-row loads issue together; running
// (m, dsum, acc) with rescale. Post-reduce scores are wave-uniform, so
// dsum needs no final reduction and no weight-ownership shuffles exist.
__global__ __launch_bounds__(256) void attn_kernel(
        const __bf16* __restrict__ hbuf, const __bf16* __restrict__ abuf,
        const __bf16* __restrict__ bbuf, const float* __restrict__ x,
        const int* __restrict__ nbr, const int* __restrict__ nbr_cnt,
        const float* __restrict__ w2, const float* __restrict__ gamma,
        const float* __restrict__ beta, float* __restrict__ out) {
    int tid = threadIdx.x;
    int w = tid >> 6, l = tid & 63;
    int i  = (blockIdx.x & 63) * 4 + w;
    int bt = blockIdx.x >> 6;
    int d2 = 2 * l;                 // this lane's dim pair {d2, d2+1}

    int cnt = nbr_cnt[i];
    int jreg = nbr[i * 64 + l];     // lane l holds neighbor l's index (l<cnt)

    bf16x2 av = *(const bf16x2*)(abuf + (size_t)(bt * NN + i) * DD + d2);
    float a0 = (float)av[0], a1 = (float)av[1];
    float2 wv = *(const float2*)(w2 + d2);
    float w20 = wv.x, w21 = wv.y;
    const __bf16* bbase = bbuf + (size_t)bt * NN * DD;
    const __bf16* hbase = hbuf + (size_t)bt * NN * DD;

    float m = -3.0e38f, dsum = 0.f, acc0 = 0.f, acc1 = 0.f;
    for (int c = 0; c < cnt; c += 4) {
        int i0 = c, i1 = c + 1, i2 = c + 2, i3 = c + 3;
        bool v1 = i1 < cnt, v2 = i2 < cnt, v3 = i3 < cnt;
        int j0 = __shfl(jreg, i0);
        int j1 = v1 ? __shfl(jreg, i1) : i;
        int j2 = v2 ? __shfl(jreg, i2) : i;
        int j3 = v3 ? __shfl(jreg, i3) : i;
        // b-rows and h-rows: 8 independent loads issued together
        bf16x2 b0 = *(const bf16x2*)(bbase + (size_t)j0 * DD + d2);
        bf16x2 b1 = *(const bf16x2*)(bbase + (size_t)j1 * DD + d2);
        bf16x2 b2 = *(const bf16x2*)(bbase + (size_t)j2 * DD + d2);
        bf16x2 b3 = *(const bf16x2*)(bbase + (size_t)j3 * DD + d2);
        bf16x2 h0 = *(const bf16x2*)(hbase + (size_t)j0 * DD + d2);
        bf16x2 h1 = *(const bf16x2*)(hbase + (size_t)j1 * DD + d2);
        bf16x2 h2 = *(const bf16x2*)(hbase + (size_t)j2 * DD + d2);
        bf16x2 h3 = *(const bf16x2*)(hbase + (size_t)j3 * DD + d2);

        float p0 = LREL(a0 + (float)b0[0]) * w20 + LREL(a1 + (float)b0[1]) * w21;
        float p1 = LREL(a0 + (float)b1[0]) * w20 + LREL(a1 + (float)b1[1]) * w21;
        float p2 = LREL(a0 + (float)b2[0]) * w20 + LREL(a1 + (float)b2[1]) * w21;
        float p3 = LREL(a0 + (float)b3[0]) * w20 + LREL(a1 + (float)b3[1]) * w21;
#pragma unroll
        for (int off = 32; off; off >>= 1) {
            p0 += __shfl_xor(p0, off);
            p1 += __shfl_xor(p1, off);
            p2 += __shfl_xor(p2, off);
            p3 += __shfl_xor(p3, off);
        }
        // online-softmax update (p* are wave-uniform now)
        float pm0 = p0;
        float pm1 = v1 ? p1 : -3.0e38f;
        float pm2 = v2 ? p2 : -3.0e38f;
        float pm3 = v3 ? p3 : -3.0e38f;
        float m_new = fmaxf(m, fmaxf(fmaxf(pm0, pm1), fmaxf(pm2, pm3)));
        float scale = __expf(m - m_new);
        float e0 = __expf(p0 - m_new);
        float e1 = v1 ? __expf(p1 - m_new) : 0.f;
        float e2 = v2 ? __expf(p2 - m_new) : 0.f;
        float e3 = v3 ? __expf(p3 - m_new) : 0.f;
        dsum = dsum * scale + (e0 + e1) + (e2 + e3);
        acc0 = acc0 * scale + e0 * (float)h0[0] + e1 * (float)h1[0]
                            + e2 * (float)h2[0] + e3 * (float)h3[0];
        acc1 = acc1 * scale + e0 * (float)h0[1] + e1 * (float)h1[1]
                            + e2 * (float)h2[1] + e3 * (float)h3[1];
        m = m_new;
    }
    float inv = 1.f / dsum;         // uniform across lanes, no reduce needed

    // ---- residual + LayerNorm + ReLU ----
    float2 xv = *(const float2*)(x + (size_t)(bt * NN + i) * DD + d2);
    float y0 = acc0 * inv + xv.x;
    float y1 = acc1 * inv + xv.y;

    float s = y0 + y1;
#pragma unroll
    for (int off = 32; off; off >>= 1) s += __shfl_xor(s, off);
    float mu = s * (1.0f / 128.0f);
    float v0 = y0 - mu, v1 = y1 - mu;
    float vs = v0 * v0 + v1 * v1;
#pragma unroll
    for (int off = 32; off; off >>= 1) vs += __shfl_xor(vs, off);
    float rstd = rsqrtf(vs * (1.0f / 128.0f) + 1e-5f);

    float2 gv = *(const float2*)(gamma + d2);
    float2 bv = *(const float2*)(beta + d2);
    float2 ov;
    ov.x = fmaxf(v0 * rstd * gv.x + bv.x, 0.0f);
    ov.y = fmaxf(v1 * rstd * gv.y + bv.y, 0.0f);
    *(float2*)(out + (size_t)(bt * NN + i) * DD + d2) = ov;
}

extern "C" void kernel_launch(void* const* d_in, const int* in_sizes, int n_in,
                              void* d_out, int out_size, void* d_ws, size_t ws_size,
                              hipStream_t stream) {
    const float* x      = (const float*)d_in[0];
    const float* adj    = (const float*)d_in[1];
    const float* weight = (const float*)d_in[2];
    const float* bias   = (const float*)d_in[3];
    const float* attw1  = (const float*)d_in[4];
    const float* attb1  = (const float*)d_in[5];
    const float* attw2  = (const float*)d_in[6];
    // d_in[7] = att_b2: uniform score shift -> cancels in softmax
    const float* gamma  = (const float*)d_in[8];
    const float* beta   = (const float*)d_in[9];
    float* out = (float*)d_out;

    char* p = (char*)d_ws;
    __bf16* hbuf = (__bf16*)p;        p += (size_t)MROWS * DD * 2;
    __bf16* abuf = (__bf16*)p;        p += (size_t)MROWS * DD * 2;
    __bf16* bbuf = (__bf16*)p;        p += (size_t)MROWS * DD * 2;
    int* nbr     = (int*)p;           p += (size_t)NN * 64 * 4;
    int* nbr_cnt = (int*)p;

    gemm2_kernel<<<MROWS / 16 * 2, 256, 0, stream>>>(x, weight, bias, attw1, attb1,
                                                     adj, hbuf, abuf, bbuf,
                                                     nbr, nbr_cnt);
    attn_kernel<<<NN / 4 * BT, 256, 0, stream>>>(hbuf, abuf, bbuf, x, nbr, nbr_cnt,
                                                 attw2, gamma, beta, out);
}